// Round 1
// baseline (183.110 us; speedup 1.0000x reference)
//
#include <hip/hip_runtime.h>
#include <stdint.h>

// NormalizedLoss: batched chamfer + coverage/quality on point clouds.
// x: [32, 2048, 3] fp32, y: [32, 2048, 3] fp32 -> out: [val, cd, cov, qual] fp32.
//
// Strategy: never materialize the 32x2048x2048 distance matrix.
//  - pack_kernel: q-side preprocess  (-2q0, -2q1, -2q2, qn [+BIG if invalid])
//  - nn_kernel:   for each p point, min/argmin of d' = qn - 2*dot over a q-chunk
//                 (3 FMA + min/sel per pair), combined across chunks via
//                 atomicMin on sortable-packed (key<<32 | idx) u64
//  - finalize:    unpack min, add pn, per-batch sums/counts, scatter hit bits
//  - final:       per-batch hit sums, assemble the 4 scalars

#define BB 32
#define NP 2048                 // points per cloud (N == M)
#define NPTS (BB * NP)          // 65536 per side
#define QCHUNK 4
#define QLEN (NP / QCHUNK)      // 512
#define NCHUNK 8                // 2048 / 256 p-points per block
#define BIGF 1e10f

typedef unsigned long long u64;

__global__ __launch_bounds__(256) void pack_kernel(const float* __restrict__ x,
                                                   const float* __restrict__ y,
                                                   float4* __restrict__ pq) {
  int t = blockIdx.x * 256 + threadIdx.x;  // 0 .. 2*NPTS
  int side = t >> 16;                      // NPTS = 65536 = 2^16
  int i = t & (NPTS - 1);
  const float* src = side ? y : x;         // pq[0..NPTS) = packed x, then packed y
  float v0 = src[3 * i], v1 = src[3 * i + 1], v2 = src[3 * i + 2];
  float s = v0 + v1 + v2;                  // row considered invalid iff sum == 0
  float qn = v0 * v0 + v1 * v1 + v2 * v2;
  if (s == 0.0f) qn += BIGF;               // push invalid q rows out of every min
  pq[side * NPTS + i] = make_float4(-2.0f * v0, -2.0f * v1, -2.0f * v2, qn);
}

__global__ __launch_bounds__(256) void nn_kernel(const float* __restrict__ x,
                                                 const float* __restrict__ y,
                                                 const float4* __restrict__ pq,
                                                 u64* __restrict__ argp) {
  int bid = blockIdx.x;
  int side = bid >> 10;  // 1024 blocks per side: 32 b * 8 nchunk * 4 qchunk
  int r = bid & 1023;
  int b = r >> 5;
  int c = (r >> 2) & 7;  // which 256 p-points
  int qc = r & 3;        // which 512 q-points

  __shared__ float4 qs[QLEN];  // 8 KB
  const float4* qbase = pq + (side ? 0 : NPTS) + b * NP + qc * QLEN;
  for (int j = threadIdx.x; j < QLEN; j += 256) qs[j] = qbase[j];

  int pi = c * 256 + threadIdx.x;
  const float* praw = (side ? y : x) + (b * NP + pi) * 3;
  float p0 = praw[0], p1 = praw[1], p2 = praw[2];
  __syncthreads();

  float best = 3.0e38f;
  int bj = 0;
#pragma unroll 8
  for (int j = 0; j < QLEN; ++j) {
    float4 q = qs[j];  // wave-uniform broadcast read
    float d = fmaf(q.x, p0, fmaf(q.y, p1, fmaf(q.z, p2, q.w)));
    if (d < best) { best = d; bj = j; }  // strict < keeps first index (jnp.argmin)
  }

  // sortable encode: ascending float order -> ascending unsigned order
  unsigned ub = __float_as_uint(best);
  unsigned su = (ub & 0x80000000u) ? ~ub : (ub | 0x80000000u);
  u64 key = ((u64)su << 32) | (unsigned)(qc * QLEN + bj);
  atomicMin(&argp[side * NPTS + b * NP + pi], key);  // ties -> smallest idx = first
}

__global__ __launch_bounds__(256) void finalize_kernel(const float* __restrict__ x,
                                                       const float* __restrict__ y,
                                                       const u64* __restrict__ argp,
                                                       int* __restrict__ hit,
                                                       float* __restrict__ sums,
                                                       float* __restrict__ cnts) {
  int bid = blockIdx.x;  // 512 blocks: side * 32 b * 8 chunks
  int side = bid >> 8;
  int b = (bid >> 3) & 31;
  int c = bid & 7;
  int pi = c * 256 + threadIdx.x;
  const float* praw = (side ? y : x) + (b * NP + pi) * 3;
  float p0 = praw[0], p1 = praw[1], p2 = praw[2];
  bool valid = (p0 + p1 + p2) != 0.0f;

  u64 key = argp[(size_t)side * NPTS + b * NP + pi];
  unsigned su = (unsigned)(key >> 32);
  int idx = (int)(key & 0xFFFFFFFFu);
  unsigned ub = (su & 0x80000000u) ? (su ^ 0x80000000u) : ~su;
  float dmin = __uint_as_float(ub);
  float pmin = dmin + (p0 * p0 + p1 * p1 + p2 * p2);  // restore + ||p||^2 term

  float contrib = valid ? pmin : 0.0f;
  float cntv = valid ? 1.0f : 0.0f;
  if (valid) hit[side * NPTS + b * NP + idx] = 1;  // benign write race (all write 1)

  for (int o = 32; o > 0; o >>= 1) {
    contrib += __shfl_down(contrib, o, 64);
    cntv += __shfl_down(cntv, o, 64);
  }
  __shared__ float red[8];
  int wid = threadIdx.x >> 6;
  if ((threadIdx.x & 63) == 0) { red[wid] = contrib; red[4 + wid] = cntv; }
  __syncthreads();
  if (threadIdx.x == 0) {
    float s = red[0] + red[1] + red[2] + red[3];
    float cc = red[4] + red[5] + red[6] + red[7];
    atomicAdd(&sums[side * BB + b], s);
    atomicAdd(&cnts[side * BB + b], cc);
  }
}

__global__ __launch_bounds__(256) void final_kernel(const int* __restrict__ hit,
                                                    const float* __restrict__ sums,
                                                    const float* __restrict__ cnts,
                                                    float* __restrict__ out) {
  __shared__ float red[8];
  int tid = threadIdx.x;
  float cd_s = 0.f, cov_s = 0.f, qual_s = 0.f;
  for (int b = 0; b < BB; ++b) {
    float hy = 0.f, hx = 0.f;
    for (int i = tid; i < NP; i += 256) {
      hy += (float)hit[b * NP + i];          // side 0 scatter: hits over y indices
      hx += (float)hit[NPTS + b * NP + i];   // side 1 scatter: hits over x indices
    }
    for (int o = 32; o > 0; o >>= 1) {
      hy += __shfl_down(hy, o, 64);
      hx += __shfl_down(hx, o, 64);
    }
    int wid = tid >> 6;
    if ((tid & 63) == 0) { red[wid] = hy; red[4 + wid] = hx; }
    __syncthreads();
    if (tid == 0) {
      float hyT = red[0] + red[1] + red[2] + red[3];
      float hxT = red[4] + red[5] + red[6] + red[7];
      float nx = cnts[b], ny = cnts[BB + b];
      cd_s += sums[b] / nx + sums[BB + b] / ny;
      cov_s += hyT / ny;
      qual_s += hxT / nx;
    }
    __syncthreads();
  }
  if (tid == 0) {
    float cd = cd_s / (float)BB;
    float cov = cov_s / (float)BB;
    float qual = qual_s / (float)BB;
    out[0] = cd - 1e-4f * cov - 1e-4f * qual;  // WCD*cd - WCOV*cov - WQUAL*qual
    out[1] = cd;
    out[2] = cov;
    out[3] = qual;
  }
}

extern "C" void kernel_launch(void* const* d_in, const int* in_sizes, int n_in,
                              void* d_out, int out_size, void* d_ws, size_t ws_size,
                              hipStream_t stream) {
  const float* x = (const float*)d_in[0];
  const float* y = (const float*)d_in[1];
  float* out = (float*)d_out;
  char* ws = (char*)d_ws;

  // ws layout:
  //   [0, 1MB)              argp: 2*NPTS u64, memset 0xFF (== u64 max)
  //   [1MB, 1.5MB)          hit:  2*NPTS int, memset 0
  //   [1.5MB, +256B)        sums: 2*BB float   (zeroed with hit region)
  //   [.. +256B)            cnts: 2*BB float
  //   [1.5MB+1KB, +2MB)     pq:   2*NPTS float4 (written fully by pack_kernel)
  u64* argp = (u64*)ws;
  int* hit = (int*)(ws + 2ull * NPTS * 8);
  float* sums = (float*)(ws + 2ull * NPTS * 8 + 2ull * NPTS * 4);
  float* cnts = sums + 2 * BB;
  float4* pq = (float4*)(ws + 2ull * NPTS * 8 + 2ull * NPTS * 4 + 1024);

  hipMemsetAsync(argp, 0xFF, 2ull * NPTS * 8, stream);
  hipMemsetAsync(hit, 0, 2ull * NPTS * 4 + 1024, stream);

  pack_kernel<<<2 * NPTS / 256, 256, 0, stream>>>(x, y, pq);
  nn_kernel<<<2 * BB * NCHUNK * QCHUNK, 256, 0, stream>>>(x, y, pq, argp);
  finalize_kernel<<<2 * BB * NCHUNK, 256, 0, stream>>>(x, y, argp, hit, sums, cnts);
  final_kernel<<<1, 256, 0, stream>>>(hit, sums, cnts, out);
}

// Round 2
// 110.400 us; speedup vs baseline: 1.6586x; 1.6586x over previous
//
#include <hip/hip_runtime.h>
#include <stdint.h>

// NormalizedLoss: batched chamfer + coverage/quality on point clouds.
// x: [32, 2048, 3] fp32, y: [32, 2048, 3] fp32 -> out: [val, cd, cov, qual] fp32.
//
// R2: the R1 profile showed final_kernel (single-block, 32-batch serial loop)
// at 85 us = 46% of runtime. Split into a 64-block hitsum_kernel (one block
// per side x batch, direct store, no atomics) + a 1-wave assemble_kernel.

#define BB 32
#define NP 2048                 // points per cloud (N == M)
#define NPTS (BB * NP)          // 65536 per side
#define QCHUNK 4
#define QLEN (NP / QCHUNK)      // 512
#define NCHUNK 8                // 2048 / 256 p-points per block
#define BIGF 1e10f

typedef unsigned long long u64;

__global__ __launch_bounds__(256) void pack_kernel(const float* __restrict__ x,
                                                   const float* __restrict__ y,
                                                   float4* __restrict__ pq) {
  int t = blockIdx.x * 256 + threadIdx.x;  // 0 .. 2*NPTS
  int side = t >> 16;                      // NPTS = 65536 = 2^16
  int i = t & (NPTS - 1);
  const float* src = side ? y : x;         // pq[0..NPTS) = packed x, then packed y
  float v0 = src[3 * i], v1 = src[3 * i + 1], v2 = src[3 * i + 2];
  float s = v0 + v1 + v2;                  // row considered invalid iff sum == 0
  float qn = v0 * v0 + v1 * v1 + v2 * v2;
  if (s == 0.0f) qn += BIGF;               // push invalid q rows out of every min
  pq[side * NPTS + i] = make_float4(-2.0f * v0, -2.0f * v1, -2.0f * v2, qn);
}

__global__ __launch_bounds__(256) void nn_kernel(const float* __restrict__ x,
                                                 const float* __restrict__ y,
                                                 const float4* __restrict__ pq,
                                                 u64* __restrict__ argp) {
  int bid = blockIdx.x;
  int side = bid >> 10;  // 1024 blocks per side: 32 b * 8 nchunk * 4 qchunk
  int r = bid & 1023;
  int b = r >> 5;
  int c = (r >> 2) & 7;  // which 256 p-points
  int qc = r & 3;        // which 512 q-points

  __shared__ float4 qs[QLEN];  // 8 KB
  const float4* qbase = pq + (side ? 0 : NPTS) + b * NP + qc * QLEN;
  for (int j = threadIdx.x; j < QLEN; j += 256) qs[j] = qbase[j];

  int pi = c * 256 + threadIdx.x;
  const float* praw = (side ? y : x) + (b * NP + pi) * 3;
  float p0 = praw[0], p1 = praw[1], p2 = praw[2];
  __syncthreads();

  float best = 3.0e38f;
  int bj = 0;
#pragma unroll 8
  for (int j = 0; j < QLEN; ++j) {
    float4 q = qs[j];  // wave-uniform broadcast read
    float d = fmaf(q.x, p0, fmaf(q.y, p1, fmaf(q.z, p2, q.w)));
    if (d < best) { best = d; bj = j; }  // strict < keeps first index (jnp.argmin)
  }

  // sortable encode: ascending float order -> ascending unsigned order
  unsigned ub = __float_as_uint(best);
  unsigned su = (ub & 0x80000000u) ? ~ub : (ub | 0x80000000u);
  u64 key = ((u64)su << 32) | (unsigned)(qc * QLEN + bj);
  atomicMin(&argp[side * NPTS + b * NP + pi], key);  // ties -> smallest idx = first
}

__global__ __launch_bounds__(256) void finalize_kernel(const float* __restrict__ x,
                                                       const float* __restrict__ y,
                                                       const u64* __restrict__ argp,
                                                       int* __restrict__ hit,
                                                       float* __restrict__ sums,
                                                       float* __restrict__ cnts) {
  int bid = blockIdx.x;  // 512 blocks: side * 32 b * 8 chunks
  int side = bid >> 8;
  int b = (bid >> 3) & 31;
  int c = bid & 7;
  int pi = c * 256 + threadIdx.x;
  const float* praw = (side ? y : x) + (b * NP + pi) * 3;
  float p0 = praw[0], p1 = praw[1], p2 = praw[2];
  bool valid = (p0 + p1 + p2) != 0.0f;

  u64 key = argp[(size_t)side * NPTS + b * NP + pi];
  unsigned su = (unsigned)(key >> 32);
  int idx = (int)(key & 0xFFFFFFFFu);
  unsigned ub = (su & 0x80000000u) ? (su ^ 0x80000000u) : ~su;
  float dmin = __uint_as_float(ub);
  float pmin = dmin + (p0 * p0 + p1 * p1 + p2 * p2);  // restore + ||p||^2 term

  float contrib = valid ? pmin : 0.0f;
  float cntv = valid ? 1.0f : 0.0f;
  if (valid) hit[side * NPTS + b * NP + idx] = 1;  // benign write race (all write 1)

  for (int o = 32; o > 0; o >>= 1) {
    contrib += __shfl_down(contrib, o, 64);
    cntv += __shfl_down(cntv, o, 64);
  }
  __shared__ float red[8];
  int wid = threadIdx.x >> 6;
  if ((threadIdx.x & 63) == 0) { red[wid] = contrib; red[4 + wid] = cntv; }
  __syncthreads();
  if (threadIdx.x == 0) {
    float s = red[0] + red[1] + red[2] + red[3];
    float cc = red[4] + red[5] + red[6] + red[7];
    atomicAdd(&sums[side * BB + b], s);
    atomicAdd(&cnts[side * BB + b], cc);
  }
}

// One block per (side, batch): reduce the 2048-int hit row, direct store.
__global__ __launch_bounds__(256) void hitsum_kernel(const int* __restrict__ hit,
                                                     float* __restrict__ hsum) {
  int sb = blockIdx.x;  // 0..63 = side*32 + b
  float h = 0.f;
  const int* row = hit + sb * NP;
  for (int i = threadIdx.x; i < NP; i += 256) h += (float)row[i];
  for (int o = 32; o > 0; o >>= 1) h += __shfl_down(h, o, 64);
  __shared__ float red[4];
  if ((threadIdx.x & 63) == 0) red[threadIdx.x >> 6] = h;
  __syncthreads();
  if (threadIdx.x == 0) hsum[sb] = red[0] + red[1] + red[2] + red[3];
}

// Single wave: lanes 0..31 each handle one batch, shuffle-reduce, write 4 outs.
__global__ __launch_bounds__(64) void assemble_kernel(const float* __restrict__ sums,
                                                      const float* __restrict__ cnts,
                                                      const float* __restrict__ hsum,
                                                      float* __restrict__ out) {
  int b = threadIdx.x;
  float cd = 0.f, cov = 0.f, qual = 0.f;
  if (b < BB) {
    float nx = cnts[b], ny = cnts[BB + b];
    cd = sums[b] / nx + sums[BB + b] / ny;
    cov = hsum[b] / ny;        // side-0 scatter hits y indices
    qual = hsum[BB + b] / nx;  // side-1 scatter hits x indices
  }
  for (int o = 32; o > 0; o >>= 1) {
    cd += __shfl_down(cd, o, 64);
    cov += __shfl_down(cov, o, 64);
    qual += __shfl_down(qual, o, 64);
  }
  if (threadIdx.x == 0) {
    cd /= (float)BB; cov /= (float)BB; qual /= (float)BB;
    out[0] = cd - 1e-4f * cov - 1e-4f * qual;  // WCD*cd - WCOV*cov - WQUAL*qual
    out[1] = cd;
    out[2] = cov;
    out[3] = qual;
  }
}

extern "C" void kernel_launch(void* const* d_in, const int* in_sizes, int n_in,
                              void* d_out, int out_size, void* d_ws, size_t ws_size,
                              hipStream_t stream) {
  const float* x = (const float*)d_in[0];
  const float* y = (const float*)d_in[1];
  float* out = (float*)d_out;
  char* ws = (char*)d_ws;

  // ws layout:
  //   [0, 1MB)              argp: 2*NPTS u64, memset 0xFF (== u64 max)
  //   [1MB, 1.5MB)          hit:  2*NPTS int, memset 0
  //   [1.5MB, +256B)        sums: 2*BB float   (zeroed with hit region)
  //   [.. +256B)            cnts: 2*BB float
  //   [.. +256B)            hsum: 2*BB float   (written fully, no init needed)
  //   [1.5MB+1KB, +2MB)     pq:   2*NPTS float4 (written fully by pack_kernel)
  u64* argp = (u64*)ws;
  int* hit = (int*)(ws + 2ull * NPTS * 8);
  float* sums = (float*)(ws + 2ull * NPTS * 8 + 2ull * NPTS * 4);
  float* cnts = sums + 2 * BB;
  float* hsum = cnts + 2 * BB;
  float4* pq = (float4*)(ws + 2ull * NPTS * 8 + 2ull * NPTS * 4 + 1024);

  hipMemsetAsync(argp, 0xFF, 2ull * NPTS * 8, stream);
  hipMemsetAsync(hit, 0, 2ull * NPTS * 4 + 512, stream);  // hit + sums + cnts

  pack_kernel<<<2 * NPTS / 256, 256, 0, stream>>>(x, y, pq);
  nn_kernel<<<2 * BB * NCHUNK * QCHUNK, 256, 0, stream>>>(x, y, pq, argp);
  finalize_kernel<<<2 * BB * NCHUNK, 256, 0, stream>>>(x, y, argp, hit, sums, cnts);
  hitsum_kernel<<<2 * BB, 256, 0, stream>>>(hit, hsum);
  assemble_kernel<<<1, 64, 0, stream>>>(sums, cnts, hsum, out);
}

// Round 3
// 102.973 us; speedup vs baseline: 1.7782x; 1.0721x over previous
//
#include <hip/hip_runtime.h>
#include <stdint.h>

// NormalizedLoss: batched chamfer + coverage/quality on point clouds.
// x: [32, 2048, 3] fp32, y: [32, 2048, 3] fp32 -> out: [val, cd, cov, qual] fp32.
//
// R3: rocprof showed nn_kernel LDS-issue-bound (1 broadcast ds_read_b128 per
// pair-column per wave = 16K LDS instrs/CU ~= 44 us) and ~65 us of small-
// dispatch overhead. Fix:
//  - P=4 register blocking: each thread holds 4 p-points -> 4x fewer LDS reads
//  - intra-block q-split: 4 waves x 512-q quarters, merged in LDS (no cross-
//    block atomicMin, no 1MB argp memset, finalize fused into epilogue)
//  - hit scatter as 16KB atomicOr bitmask; popcount in a tiny assemble kernel
//  - pipeline: memset(16.5KB) + nn_fused + assemble = 3 dispatches (was 7)

#define BB 32
#define NP 2048
#define BIGF 1e10f

__global__ __launch_bounds__(256) void nn_fused_kernel(const float* __restrict__ x,
                                                       const float* __restrict__ y,
                                                       unsigned* __restrict__ hitmask,
                                                       float* __restrict__ sums,
                                                       float* __restrict__ cnts) {
  int bid = blockIdx.x;  // 512 blocks: side(2) x b(32) x pc(8)
  int side = bid >> 8;
  int b = (bid >> 3) & 31;
  int pc = bid & 7;

  __shared__ float4 qs[NP];        // 32KB packed q: (-2q0,-2q1,-2q2, qn[+BIG])
  __shared__ float pxn[256];       // ||p||^2 per block-local p
  __shared__ float pvalid[256];    // 1.0 if p row valid
  __shared__ float2 merged[4][256];// per-wave (best, idx) partials, 8KB
  __shared__ float red[8];

  // ---- stage all 2048 q-points of this (side, b), packed, 8 per thread ----
  const float* qraw = (side ? x : y) + b * NP * 3;
  for (int k = 0; k < 8; ++k) {
    int i = threadIdx.x + 256 * k;
    float q0 = qraw[3 * i], q1 = qraw[3 * i + 1], q2 = qraw[3 * i + 2];
    float s = q0 + q1 + q2;  // invalid q row iff coord sum == 0
    float qn = q0 * q0 + q1 * q1 + q2 * q2;
    if (s == 0.0f) qn += BIGF;  // push invalid q out of every min
    qs[i] = make_float4(-2.0f * q0, -2.0f * q1, -2.0f * q2, qn);
  }

  int w = threadIdx.x >> 6;    // wave id == q-quarter (512 q each)
  int lane = threadIdx.x & 63;

  // ---- each wave loads the SAME 256 p-points: p_local = lane + 64k ----
  const float* praw = (side ? y : x) + (b * NP + pc * 256) * 3;
  float p0[4], p1[4], p2[4];
  for (int k = 0; k < 4; ++k) {
    int pl = lane + 64 * k;
    p0[k] = praw[3 * pl];
    p1[k] = praw[3 * pl + 1];
    p2[k] = praw[3 * pl + 2];
    if (w == 0) {
      float s = p0[k] + p1[k] + p2[k];
      pxn[pl] = p0[k] * p0[k] + p1[k] * p1[k] + p2[k] * p2[k];
      pvalid[pl] = (s != 0.0f) ? 1.0f : 0.0f;
    }
  }
  __syncthreads();

  // ---- main loop: this wave's q-quarter vs its 4 p-points ----
  float best0 = 3.0e38f, best1 = 3.0e38f, best2 = 3.0e38f, best3 = 3.0e38f;
  int bj0 = 0, bj1 = 0, bj2 = 0, bj3 = 0;
  const float4* qq = &qs[w * 512];
#pragma unroll 8
  for (int j = 0; j < 512; ++j) {
    float4 q = qq[j];  // wave-uniform broadcast, amortized over 4 pairs
    float d0 = fmaf(q.x, p0[0], fmaf(q.y, p1[0], fmaf(q.z, p2[0], q.w)));
    float d1 = fmaf(q.x, p0[1], fmaf(q.y, p1[1], fmaf(q.z, p2[1], q.w)));
    float d2 = fmaf(q.x, p0[2], fmaf(q.y, p1[2], fmaf(q.z, p2[2], q.w)));
    float d3 = fmaf(q.x, p0[3], fmaf(q.y, p1[3], fmaf(q.z, p2[3], q.w)));
    if (d0 < best0) { best0 = d0; bj0 = j; }  // strict < keeps first index
    if (d1 < best1) { best1 = d1; bj1 = j; }
    if (d2 < best2) { best2 = d2; bj2 = j; }
    if (d3 < best3) { best3 = d3; bj3 = j; }
  }
  int qoff = w * 512;
  merged[w][lane +   0] = make_float2(best0, __int_as_float(qoff + bj0));
  merged[w][lane +  64] = make_float2(best1, __int_as_float(qoff + bj1));
  merged[w][lane + 128] = make_float2(best2, __int_as_float(qoff + bj2));
  merged[w][lane + 192] = make_float2(best3, __int_as_float(qoff + bj3));
  __syncthreads();

  // ---- merge quarters (ascending w + strict < == jnp.argmin tie order) ----
  int t = threadIdx.x;  // thread t owns p_local = t
  float2 e0 = merged[0][t];
  float bd = e0.x;
  int bi = __float_as_int(e0.y);
  for (int ww = 1; ww < 4; ++ww) {
    float2 e = merged[ww][t];
    if (e.x < bd) { bd = e.x; bi = __float_as_int(e.y); }
  }

  // ---- fused finalize: restore ||p||^2 term, mask, scatter, reduce ----
  float valid = pvalid[t];
  float pmin = bd + pxn[t];
  float contrib = valid * pmin;
  if (valid != 0.0f)
    atomicOr(&hitmask[(side * BB + b) * 64 + (bi >> 5)], 1u << (bi & 31));

  float cnt = valid;
  for (int o = 32; o > 0; o >>= 1) {
    contrib += __shfl_down(contrib, o, 64);
    cnt += __shfl_down(cnt, o, 64);
  }
  if (lane == 0) { red[w] = contrib; red[4 + w] = cnt; }
  __syncthreads();
  if (t == 0) {
    atomicAdd(&sums[side * BB + b], red[0] + red[1] + red[2] + red[3]);
    atomicAdd(&cnts[side * BB + b], red[4] + red[5] + red[6] + red[7]);
  }
}

// Single wave: lanes 0..31 each assemble one batch; shuffle-reduce; write 4.
__global__ __launch_bounds__(64) void assemble_kernel(const unsigned* __restrict__ hitmask,
                                                      const float* __restrict__ sums,
                                                      const float* __restrict__ cnts,
                                                      float* __restrict__ out) {
  int t = threadIdx.x;
  float cd = 0.f, cov = 0.f, qual = 0.f;
  if (t < BB) {
    float nx = cnts[t], ny = cnts[BB + t];
    int hy = 0, hx = 0;
    for (int i = 0; i < 64; ++i) hy += __popc(hitmask[t * 64 + i]);          // side0 hits y
    for (int i = 0; i < 64; ++i) hx += __popc(hitmask[(BB + t) * 64 + i]);   // side1 hits x
    cd = sums[t] / nx + sums[BB + t] / ny;
    cov = (float)hy / ny;
    qual = (float)hx / nx;
  }
  for (int o = 32; o > 0; o >>= 1) {
    cd += __shfl_down(cd, o, 64);
    cov += __shfl_down(cov, o, 64);
    qual += __shfl_down(qual, o, 64);
  }
  if (t == 0) {
    cd /= (float)BB; cov /= (float)BB; qual /= (float)BB;
    out[0] = cd - 1e-4f * cov - 1e-4f * qual;  // WCD*cd - WCOV*cov - WQUAL*qual
    out[1] = cd;
    out[2] = cov;
    out[3] = qual;
  }
}

extern "C" void kernel_launch(void* const* d_in, const int* in_sizes, int n_in,
                              void* d_out, int out_size, void* d_ws, size_t ws_size,
                              hipStream_t stream) {
  const float* x = (const float*)d_in[0];
  const float* y = (const float*)d_in[1];
  float* out = (float*)d_out;
  char* ws = (char*)d_ws;

  // ws layout: [0,16KB) hitmask (2*32 batches x 64 u32 words)
  //            [16KB, +256B) sums   [16KB+256, +256B) cnts
  unsigned* hitmask = (unsigned*)ws;
  float* sums = (float*)(ws + 16384);
  float* cnts = sums + 2 * BB;

  hipMemsetAsync(ws, 0, 16384 + 512, stream);
  nn_fused_kernel<<<2 * BB * 8, 256, 0, stream>>>(x, y, hitmask, sums, cnts);
  assemble_kernel<<<1, 64, 0, stream>>>(hitmask, sums, cnts, out);
}